// Round 5
// baseline (121.526 us; speedup 1.0000x reference)
//
#include <hip/hip_runtime.h>

// Problem dims (fixed by reference setup_inputs)
#define B_  4
#define C_  3
#define S_  5
#define M_  18
#define HW  45056            // 256*176
#define HW4 (HW/4)           // 11264 float4s per plane/channel
#define G   3                // m-planes per block (shares X/Y loads)
#define MG  (M_/G)           // 6 m-groups per (b,s)
#define SPLIT 4              // chunks per plane-group (divides HW4/TPB = 44)
#define TPB 256
#define CHUNK4 (HW4/SPLIT)   // 2816 float4s per block
#define ITERS (CHUNK4/TPB)   // 11 iterations per thread (ITERS=11 proven best)
#define NGROUP (B_*S_*MG)    // 120 plane-groups
#define NBLK (NGROUP*SPLIT)  // 480 blocks (480 % 8 == 0 -> bijective XCD swizzle)
#define NPLANE (B_*S_*M_)    // 360
#define NV (G*16)            // 48 partial values per block
#define MAGIC 0x1B7E2A3Du    // completion flag value (ws is poison-filled each
                             // iteration by the harness, which clears stale flags)

// Fused kernel: moments + (block-0) finalize.
// SYNC DESIGN (round-5 fix): NO release/acquire fences. Agent-scope RELAXED
// atomics compile to bare sc1 loads/stores (coherent at the die-level L3)
// with no buffer_wbl2 / buffer_inv. Ordering argument:
//   - each thread's part[] sc1-stores are acked at the coherence point before
//     __syncthreads() completes (it drains vmcnt(0));
//   - the flag sc1-store issues after the barrier, so any reader that sees
//     MAGIC will also see the part[] data at the coherence point;
//   - block 0 reads part[] with sc1 loads (bypasses its own, possibly stale, L2).
// The previous RELEASE-per-block design triggered 480 buffer_wbl2 L2 scans
// (~60 per XCD) -> ~35 us of L2-busy serialization with all pipes idle.
__global__ __launch_bounds__(TPB) void fused_kernel(
    const float4* __restrict__ X, const float4* __restrict__ Y,
    const float4* __restrict__ Mk, float* __restrict__ part,
    unsigned int* __restrict__ flags, float* __restrict__ out) {
  // XCD-aware bijective swizzle: each XCD's L2 holds ~1 batch of X/Y.
  int wg    = (blockIdx.x & 7) * (NBLK / 8) + (blockIdx.x >> 3);
  int group = wg / SPLIT;            // (b, s, mg)
  int chunk = wg - group * SPLIT;
  int bs    = group / MG;            // b*S_ + s
  int mg    = group - bs * MG;
  int b     = bs / S_;

  const float4* mp0 = Mk + (size_t)(bs * M_ + mg * G + 0) * HW4;
  const float4* mp1 = Mk + (size_t)(bs * M_ + mg * G + 1) * HW4;
  const float4* mp2 = Mk + (size_t)(bs * M_ + mg * G + 2) * HW4;
  const float4* xp = X + (size_t)b * (C_ * HW4);
  const float4* yp = Y + (size_t)b * (C_ * HW4);

  int base = chunk * CHUNK4 + (int)threadIdx.x;

  float aW[G];
  float a1[G][C_], a2[G][C_], a11[G][C_], a22[G][C_], a12[G][C_];
#pragma unroll
  for (int g = 0; g < G; ++g) {
    aW[g] = 0.f;
#pragma unroll
    for (int c = 0; c < C_; ++c) {
      a1[g][c]=a2[g][c]=a11[g][c]=a22[g][c]=a12[g][c]=0.f;
    }
  }

#pragma unroll
  for (int it = 0; it < ITERS; ++it) {
    int i = base + it * TPB;
    // Plain loads (no nt): mask lines are L2/L3-resident after the harness's
    // restore copy — keep that locality.
    float4 w0 = mp0[i];
    float4 w1 = mp1[i];
    float4 w2 = mp2[i];
    float wv[G][4] = {{w0.x,w0.y,w0.z,w0.w},
                      {w1.x,w1.y,w1.z,w1.w},
                      {w2.x,w2.y,w2.z,w2.w}};
    aW[0] += (w0.x + w0.y) + (w0.z + w0.w);
    aW[1] += (w1.x + w1.y) + (w1.z + w1.w);
    aW[2] += (w2.x + w2.y) + (w2.z + w2.w);
#pragma unroll
    for (int c = 0; c < C_; ++c) {
      float4 xv = xp[c * HW4 + i];
      float4 yv = yp[c * HW4 + i];
      float xvf[4] = {xv.x, xv.y, xv.z, xv.w};
      float yvf[4] = {yv.x, yv.y, yv.z, yv.w};
#pragma unroll
      for (int j = 0; j < 4; ++j) {
        float xc = xvf[j], yc = yvf[j];
        float xx = xc * xc, yy = yc * yc, xy = xc * yc;  // shared across G
#pragma unroll
        for (int g = 0; g < G; ++g) {
          float wc = wv[g][j];
          a1 [g][c] = fmaf(wc, xc, a1 [g][c]);
          a2 [g][c] = fmaf(wc, yc, a2 [g][c]);
          a11[g][c] = fmaf(wc, xx, a11[g][c]);
          a22[g][c] = fmaf(wc, yy, a22[g][c]);
          a12[g][c] = fmaf(wc, xy, a12[g][c]);
        }
      }
    }
  }

  // Pack 48 values: per plane g, [g*16+0]=msum, then per channel {wx,wy,wxx,wyy,wxy}
  float v[NV];
#pragma unroll
  for (int g = 0; g < G; ++g) {
    v[g*16 + 0] = aW[g];
#pragma unroll
    for (int c = 0; c < C_; ++c) {
      v[g*16 + 1 + c*5 + 0] = a1 [g][c];
      v[g*16 + 1 + c*5 + 1] = a2 [g][c];
      v[g*16 + 1 + c*5 + 2] = a11[g][c];
      v[g*16 + 1 + c*5 + 3] = a22[g][c];
      v[g*16 + 1 + c*5 + 4] = a12[g][c];
    }
  }

  // wave-64 butterfly reduce all 48 values (amortized fine at ITERS=11)
#pragma unroll
  for (int off = 32; off > 0; off >>= 1) {
#pragma unroll
    for (int j = 0; j < NV; ++j) v[j] += __shfl_xor(v[j], off);
  }

  __shared__ float red[TPB/64][NV];
  int lane = threadIdx.x & 63;
  int wv_  = threadIdx.x >> 6;
  if (lane == 0) {
#pragma unroll
    for (int j = 0; j < NV; ++j) red[wv_][j] = v[j];
  }
  __syncthreads();
  if (threadIdx.x < NV) {
    float s = (red[0][threadIdx.x] + red[1][threadIdx.x]) +
              (red[2][threadIdx.x] + red[3][threadIdx.x]);
    // sc1 store: lands at the die-level coherence point (visible cross-XCD),
    // no L2 writeback fence involved.
    __hip_atomic_store(&part[(size_t)wg * NV + threadIdx.x], s,
                       __ATOMIC_RELAXED, __HIP_MEMORY_SCOPE_AGENT);
  }

  // __syncthreads drains each thread's vmcnt(0) -> all part stores are at the
  // coherence point before the flag publishes.
  __syncthreads();
  if (threadIdx.x == 0) {
    __hip_atomic_store(&flags[wg], MAGIC, __ATOMIC_RELAXED,
                       __HIP_MEMORY_SCOPE_AGENT);
  }

  if (blockIdx.x != 0) return;

  // ---- Phase 2: block 0 finalizes ----
  // Relaxed sc1 polling (no buffer_inv per poll), gentle s_sleep backoff.
  for (int i = threadIdx.x; i < NBLK; i += TPB) {
    while (__hip_atomic_load(&flags[i], __ATOMIC_RELAXED,
                             __HIP_MEMORY_SCOPE_AGENT) != MAGIC) {
      __builtin_amdgcn_s_sleep(2);
    }
  }
  __syncthreads();

  __shared__ float csS[NPLANE], ssS[NPLANE];
  __shared__ double csb[B_*S_], ssb[B_*S_];
  int t = threadIdx.x;

  // Exact affine rescale of raw moments in double:
  //   xs = 0.5x + 0.5  =>  E[w*xs]    = 0.5*S1 + 0.5*W
  //                        E[w*xs^2]  = 0.25*S11 + 0.5*S1 + 0.25*W
  //                        E[w*xs*ys] = 0.25*(S12 + S1 + S2 + W)
  for (int p = t; p < NPLANE; p += TPB) {
    int pbs  = p / M_;
    int mrem = p - pbs * M_;
    int pmg  = mrem / G;
    int g    = mrem - pmg * G;
    int grp  = pbs * MG + pmg;

    double s[16];
#pragma unroll
    for (int j = 0; j < 16; ++j) s[j] = 0.0;
    for (int ch = 0; ch < SPLIT; ++ch) {
      const float* pp = part + (size_t)(grp * SPLIT + ch) * NV + g * 16;
#pragma unroll
      for (int j = 0; j < 16; ++j) {
        // sc1 load: bypass possibly-stale local L2 copies of part lines.
        float f = __hip_atomic_load(&pp[j], __ATOMIC_RELAXED,
                                    __HIP_MEMORY_SCOPE_AGENT);
        s[j] += (double)f;
      }
    }
    const double C1d = 1e-4, C2d = 9e-4;
    double W = s[0];
    double inv = 1.0 / (W + 1e-6);
    double csAcc = 0.0, ssAcc = 0.0;
#pragma unroll
    for (int c = 0; c < C_; ++c) {
      double S1  = s[1 + c*5 + 0];
      double S2  = s[1 + c*5 + 1];
      double S11 = s[1 + c*5 + 2];
      double S22 = s[1 + c*5 + 3];
      double S12 = s[1 + c*5 + 4];
      double mu1  = (0.5*S1 + 0.5*W) * inv;
      double mu2  = (0.5*S2 + 0.5*W) * inv;
      double mu11 = (0.25*S11 + 0.5*S1 + 0.25*W) * inv;
      double mu22 = (0.25*S22 + 0.5*S2 + 0.25*W) * inv;
      double mu12 = (0.25*(S12 + S1 + S2 + W)) * inv;
      double m1s = mu1*mu1, m2s = mu2*mu2, m12 = mu1*mu2;
      double sig1  = mu11 - m1s;
      double sig2  = mu22 - m2s;
      double sig12 = mu12 - m12;
      double cs   = (2.0*sig12 + C2d) / (sig1 + sig2 + C2d);
      double ssim = (2.0*m12 + C1d) / (m1s + m2s + C1d) * cs;
      if (cs   < 0.0) cs   = 0.0;
      if (ssim < 0.0) ssim = 0.0;
      csAcc += cs; ssAcc += ssim;
    }
    csS[p] = (float)csAcc;
    ssS[p] = (float)ssAcc;
  }
  __syncthreads();

  if (t < B_*S_) {  // t = b*S_ + s
    double cb = 0.0, sb = 0.0;
    for (int m = 0; m < M_; ++m) { cb += (double)csS[t*M_ + m]; sb += (double)ssS[t*M_ + m]; }
    csb[t] = cb / (double)(M_*C_);
    ssb[t] = sb / (double)(M_*C_);
  }
  __syncthreads();

  if (t == 0) {
    double acc = 0.0;
    for (int bb = 0; bb < B_; ++bb) {
      double pr = ssb[bb*S_ + (S_-1)];
      for (int s = 0; s < S_-1; ++s) pr *= csb[bb*S_ + s];
      acc += pr;
    }
    out[0] = (float)(acc / (double)B_);
  }
}

extern "C" void kernel_launch(void* const* d_in, const int* in_sizes, int n_in,
                              void* d_out, int out_size, void* d_ws, size_t ws_size,
                              hipStream_t stream) {
  (void)in_sizes; (void)n_in; (void)out_size; (void)ws_size;
  const float4* X  = (const float4*)d_in[0];
  const float4* Y  = (const float4*)d_in[1];
  const float4* Mk = (const float4*)d_in[2];
  float* part = (float*)d_ws;                               // 480*48*4 = 92160 B
  unsigned int* flags = (unsigned int*)((char*)d_ws + (size_t)NBLK * NV * 4);
  float* out  = (float*)d_out;

  hipLaunchKernelGGL(fused_kernel, dim3(NBLK), dim3(TPB), 0, stream,
                     X, Y, Mk, part, flags, out);
}

// Round 6
// 116.361 us; speedup vs baseline: 1.0444x; 1.0444x over previous
//
#include <hip/hip_runtime.h>

// Problem dims (fixed by reference setup_inputs)
#define B_  4
#define C_  3
#define S_  5
#define M_  18
#define HW  45056            // 256*176
#define HW4 (HW/4)           // 11264 float4s per plane/channel
#define SPLIT 4              // blocks per (b,s,m) plane (divides HW4/TPB = 44)
#define TPB 256
#define CHUNK4 (HW4/SPLIT)   // 2816 float4s per block
#define ITERS (CHUNK4/TPB)   // 11 iterations per thread (proven best)
#define NPLANE (B_*S_*M_)    // 360
#define NBLK (NPLANE*SPLIT)  // 1440 blocks (1440 % 8 == 0 -> bijective XCD swizzle)

// Two-kernel design (deliberate, after fused-flag experiments R4/R5):
//  - single-kernel fusion with cross-XCD flag sync costs either a per-block
//    buffer_wbl2 fence storm (R4: 45us, all pipes idle) or un-vectorizable
//    sc1 coherence-point loads in finalize (R5: 70us). The inter-kernel
//    dispatch boundary performs the same coherence exactly once, ~free.
//  - 1440 blocks (5.6/CU, ~22 waves/CU) is the proven latency-hiding grid;
//    480-block variants measured latency-bound (R4: HBM 10%, VALU 13%).

// Kernel A: per-(plane,chunk) partial sums of the 16 weighted RAW moments.
// Rescale is deferred to the epilogue (exact affine transform in double).
__global__ __launch_bounds__(TPB) void moments_kernel(
    const float4* __restrict__ X, const float4* __restrict__ Y,
    const float4* __restrict__ Mk, float* __restrict__ part) {
  // XCD-aware bijective swizzle: consecutive XCD slots get consecutive work
  // chunks -> each XCD's L2 holds ~1 batch of X/Y across its resident blocks.
  int wg    = (blockIdx.x & 7) * (NBLK / 8) + (blockIdx.x >> 3);
  int plane = wg / SPLIT;           // (b,s,m)
  int chunk = wg - plane * SPLIT;
  int b     = plane / (S_ * M_);

  const float4* mp = Mk + (size_t)plane * HW4;
  const float4* xp = X  + (size_t)b * (C_ * HW4);
  const float4* yp = Y  + (size_t)b * (C_ * HW4);

  int base = chunk * CHUNK4 + (int)threadIdx.x;

  float aW = 0.f;
  float a1[C_], a2[C_], a11[C_], a22[C_], a12[C_];
#pragma unroll
  for (int c = 0; c < C_; ++c) { a1[c]=a2[c]=a11[c]=a22[c]=a12[c]=0.f; }

#pragma unroll
  for (int it = 0; it < ITERS; ++it) {
    int i = base + it * TPB;
    // Plain cached loads: mask lines are L2/L3-resident after the harness's
    // restore copy; X/Y (4.3 MB total) live in each XCD's L2.
    float4 w  = mp[i];
    aW += (w.x + w.y) + (w.z + w.w);
    float wf[4] = {w.x, w.y, w.z, w.w};
#pragma unroll
    for (int c = 0; c < C_; ++c) {
      float4 xv = xp[c * HW4 + i];
      float4 yv = yp[c * HW4 + i];
      float xf[4] = {xv.x, xv.y, xv.z, xv.w};
      float yf[4] = {yv.x, yv.y, yv.z, yv.w};
#pragma unroll
      for (int j = 0; j < 4; ++j) {
        float xc = xf[j], yc = yf[j], wc = wf[j];
        float wx = wc * xc;
        float wy = wc * yc;
        a1 [c] += wx;
        a2 [c] += wy;
        a11[c]  = fmaf(wx, xc, a11[c]);
        a22[c]  = fmaf(wy, yc, a22[c]);
        a12[c]  = fmaf(wx, yc, a12[c]);
      }
    }
  }

  // Pack 16 values: [0]=msum, then per channel {wx, wy, wxx, wyy, wxy} (raw)
  float v[16];
  v[0] = aW;
#pragma unroll
  for (int c = 0; c < C_; ++c) {
    v[1 + c*5 + 0] = a1[c];
    v[1 + c*5 + 1] = a2[c];
    v[1 + c*5 + 2] = a11[c];
    v[1 + c*5 + 3] = a22[c];
    v[1 + c*5 + 4] = a12[c];
  }

  // wave-64 butterfly reduce (96 shfl+add ~ 17% of the 11-iter main loop)
#pragma unroll
  for (int off = 32; off > 0; off >>= 1) {
#pragma unroll
    for (int j = 0; j < 16; ++j) v[j] += __shfl_xor(v[j], off);
  }

  __shared__ float red[TPB/64][16];
  int lane = threadIdx.x & 63;
  int wv   = threadIdx.x >> 6;
  if (lane == 0) {
#pragma unroll
    for (int j = 0; j < 16; ++j) red[wv][j] = v[j];
  }
  __syncthreads();
  if (threadIdx.x < 16) {
    float s = (red[0][threadIdx.x] + red[1][threadIdx.x]) +
              (red[2][threadIdx.x] + red[3][threadIdx.x]);
    part[(size_t)wg * 16 + threadIdx.x] = s;
  }
}

// Kernel B: tiny epilogue, one block. Plain loads (kernel-boundary coherence);
// consecutive scalar reads -> compiler clusters into dwordx4.
// Exact affine rescale of raw moments in double:
//   xs = 0.5x + 0.5  =>  E[w*xs]    = 0.5*S1 + 0.5*W
//                        E[w*xs^2]  = 0.25*S11 + 0.5*S1 + 0.25*W
//                        E[w*xs*ys] = 0.25*(S12 + S1 + S2 + W)
__global__ __launch_bounds__(384) void finalize_kernel(
    const float* __restrict__ part, float* __restrict__ out) {
  __shared__ float csS[NPLANE], ssS[NPLANE];
  __shared__ double csb[B_*S_], ssb[B_*S_];
  int t = threadIdx.x;

  if (t < NPLANE) {
    double s[16];
#pragma unroll
    for (int j = 0; j < 16; ++j) s[j] = 0.0;
    for (int ch = 0; ch < SPLIT; ++ch) {
      const float* p = part + (size_t)(t * SPLIT + ch) * 16;
#pragma unroll
      for (int j = 0; j < 16; ++j) s[j] += (double)p[j];
    }
    const double C1d = 1e-4, C2d = 9e-4;
    double W = s[0];
    double inv = 1.0 / (W + 1e-6);
    double csAcc = 0.0, ssAcc = 0.0;
#pragma unroll
    for (int c = 0; c < C_; ++c) {
      double S1  = s[1 + c*5 + 0];
      double S2  = s[1 + c*5 + 1];
      double S11 = s[1 + c*5 + 2];
      double S22 = s[1 + c*5 + 3];
      double S12 = s[1 + c*5 + 4];
      double mu1  = (0.5*S1 + 0.5*W) * inv;
      double mu2  = (0.5*S2 + 0.5*W) * inv;
      double mu11 = (0.25*S11 + 0.5*S1 + 0.25*W) * inv;
      double mu22 = (0.25*S22 + 0.5*S2 + 0.25*W) * inv;
      double mu12 = (0.25*(S12 + S1 + S2 + W)) * inv;
      double m1s = mu1*mu1, m2s = mu2*mu2, m12 = mu1*mu2;
      double sig1  = mu11 - m1s;
      double sig2  = mu22 - m2s;
      double sig12 = mu12 - m12;
      double cs   = (2.0*sig12 + C2d) / (sig1 + sig2 + C2d);
      double ssim = (2.0*m12 + C1d) / (m1s + m2s + C1d) * cs;
      if (cs   < 0.0) cs   = 0.0;
      if (ssim < 0.0) ssim = 0.0;
      csAcc += cs; ssAcc += ssim;
    }
    csS[t] = (float)csAcc;
    ssS[t] = (float)ssAcc;
  }
  __syncthreads();

  if (t < B_*S_) {  // t = b*S_ + s
    double cb = 0.0, sb = 0.0;
    for (int m = 0; m < M_; ++m) { cb += (double)csS[t*M_ + m]; sb += (double)ssS[t*M_ + m]; }
    csb[t] = cb / (double)(M_*C_);
    ssb[t] = sb / (double)(M_*C_);
  }
  __syncthreads();

  if (t == 0) {
    double acc = 0.0;
    for (int b = 0; b < B_; ++b) {
      double p = ssb[b*S_ + (S_-1)];
      for (int s = 0; s < S_-1; ++s) p *= csb[b*S_ + s];
      acc += p;
    }
    out[0] = (float)(acc / (double)B_);
  }
}

extern "C" void kernel_launch(void* const* d_in, const int* in_sizes, int n_in,
                              void* d_out, int out_size, void* d_ws, size_t ws_size,
                              hipStream_t stream) {
  (void)in_sizes; (void)n_in; (void)out_size; (void)ws_size;
  const float4* X  = (const float4*)d_in[0];
  const float4* Y  = (const float4*)d_in[1];
  const float4* Mk = (const float4*)d_in[2];
  float* part = (float*)d_ws;        // 1440*16*4 = 92160 B
  float* out  = (float*)d_out;

  hipLaunchKernelGGL(moments_kernel, dim3(NBLK), dim3(TPB), 0, stream,
                     X, Y, Mk, part);
  hipLaunchKernelGGL(finalize_kernel, dim3(1), dim3(384), 0, stream, part, out);
}